// Round 9
// baseline (527.196 us; speedup 1.0000x reference)
//
#include <hip/hip_runtime.h>
#include <cstdint>
#include <cstddef>

#define E 1024
#define NB 32768
#define BM 128
#define BN 128

typedef __attribute__((ext_vector_type(4))) float f32x4;
typedef __attribute__((ext_vector_type(2))) float f32x2;
typedef __attribute__((ext_vector_type(8))) short bf16x8;

__device__ __forceinline__ short f2bfs(float x) {
    __bf16 h = (__bf16)x;
    return __builtin_bit_cast(short, h);
}
__device__ __forceinline__ float bf2f(short u) {
    union { unsigned u; float f; } v;
    v.u = ((unsigned)(unsigned short)u) << 16;
    return v.f;
}
__device__ __forceinline__ bf16x8 cvt8(f32x4 lo, f32x4 hi) {
    bf16x8 r;
#pragma unroll
    for (int j = 0; j < 4; ++j) { r[j] = f2bfs(lo[j]); r[j + 4] = f2bfs(hi[j]); }
    return r;
}
__device__ __forceinline__ int pack2(f32x2 v) {
    unsigned lo = (unsigned short)f2bfs(v[0]);
    unsigned hi = (unsigned short)f2bfs(v[1]);
    return (int)(lo | (hi << 16));
}

__device__ __forceinline__ void gload16(const void* g, void* l) {
    __builtin_amdgcn_global_load_lds(
        (__attribute__((address_space(1))) void*)g,
        (__attribute__((address_space(3))) void*)l, 16, 0, 0);
}

// ---------------- transpose f32 -> bf16 (Wv -> WvT) ----------------
__global__ __launch_bounds__(256) void wv_transpose(const float* W0, short* T0,
                                                    const float* W1, short* T1) {
    const float* W = blockIdx.z ? W1 : W0;
    short* T = blockIdx.z ? T1 : T0;
    __shared__ float tile[32][33];
    const int j0 = blockIdx.x * 32, i0 = blockIdx.y * 32;
    const int tx = threadIdx.x, ty = threadIdx.y; // (32,8)
#pragma unroll
    for (int r = 0; r < 4; ++r)
        tile[ty + 8 * r][tx] = W[(size_t)(i0 + ty + 8 * r) * E + j0 + tx];
    __syncthreads();
#pragma unroll
    for (int r = 0; r < 4; ++r)
        T[(size_t)(j0 + ty + 8 * r) * E + i0 + tx] = f2bfs(tile[tx][ty + 8 * r]);
}

// ---------------- c[n] = scale * (sum_i O[n][i]*bv[i] + ob[n]) ----------------
__global__ __launch_bounds__(256) void bias_fuse(const float* O0, const float* bv0, const float* ob0, const float* s0, float* c0,
                                                 const float* O1, const float* bv1, const float* ob1, const float* s1, float* c1) {
    const float* O  = blockIdx.z ? O1 : O0;
    const float* bv = blockIdx.z ? bv1 : bv0;
    const float* ob = blockIdx.z ? ob1 : ob0;
    const float* sc = blockIdx.z ? s1 : s0;
    float* c = blockIdx.z ? c1 : c0;
    const int n = blockIdx.x, t = threadIdx.x;
    float s = 0.f;
    for (int i = t; i < E; i += 256) s += O[(size_t)n * E + i] * bv[i];
#pragma unroll
    for (int o = 32; o; o >>= 1) s += __shfl_down(s, o);
    __shared__ float rs[4];
    if ((t & 63) == 0) rs[t >> 6] = s;
    __syncthreads();
    if (t == 0) c[n] = sc[0] * (rs[0] + rs[1] + rs[2] + rs[3] + ob[n]);
}

// ---------------- small GEMM (round-3 proven): C = scale * A @ B^T ----------------
struct GemmArgs {
    const char* A;
    const short* B;
    const float* bias;
    const float* scale;
    char* C;
};

__global__ __launch_bounds__(256, 3) void gemm_bt(GemmArgs g0, GemmArgs g1,
                                                  int mb, int arstride, int crstride) {
    const int nwg = gridDim.x;
    const int q = nwg >> 3;
    const int wgid = (blockIdx.x & 7) * q + (blockIdx.x >> 3);
    const int per = mb * 8;
    const int z = wgid / per;
    const int rem = wgid - z * per;
    const int bx = rem >> 3;
    const int by = rem & 7;
    GemmArgs ga = z ? g1 : g0;

    constexpr int ABYTES = 16384;
    constexpr int BUFB = ABYTES + 8192;
    __shared__ __align__(16) char lds[2][BUFB];

    const int t = threadIdx.x;
    const int l = t & 63, w = t >> 6;
    const int am0 = bx * BM, bn0 = by * BN;

    const char* gA[4];
#pragma unroll
    for (int i = 0; i < 4; ++i) {
        int c = i * 4 + w;
        int row = c * 8 + (l >> 3);
        int slot = (l & 7) ^ (row & 7);
        gA[i] = ga.A + (size_t)(am0 + row) * arstride + slot * 16;
    }
    const short* gB[2];
#pragma unroll
    for (int i = 0; i < 2; ++i) {
        int c = i * 4 + w;
        int row = c * 16 + (l >> 2);
        int slot = (l & 3) ^ ((row >> 1) & 3);
        gB[i] = ga.B + (size_t)(bn0 + row) * E + slot * 8;
    }

    auto stage = [&](int buf, int kt) {
#pragma unroll
        for (int i = 0; i < 4; ++i)
            gload16(gA[i] + (size_t)kt * 4, &lds[buf][(i * 4 + w) * 1024]);
#pragma unroll
        for (int i = 0; i < 2; ++i)
            gload16(gB[i] + kt, &lds[buf][ABYTES + (i * 4 + w) * 1024]);
    };

    const int wm = w >> 1, wn = w & 1;
    const int r16 = l & 15, kg = l >> 4;
    int aoff[4][2], boff[4];
#pragma unroll
    for (int m = 0; m < 4; ++m) {
        int row = wm * 64 + m * 16 + r16;
        aoff[m][0] = row * 128 + ((kg * 2) ^ (row & 7)) * 16;
        aoff[m][1] = row * 128 + ((kg * 2 + 1) ^ (row & 7)) * 16;
    }
#pragma unroll
    for (int n = 0; n < 4; ++n) {
        int row = wn * 64 + n * 16 + r16;
        boff[n] = ABYTES + row * 64 + (kg ^ ((row >> 1) & 3)) * 16;
    }

    f32x4 acc[4][4] = {};

    auto compute = [&](int buf) {
        bf16x8 a[4], b[4];
#pragma unroll
        for (int m = 0; m < 4; ++m) {
            f32x4 lo = *(const f32x4*)&lds[buf][aoff[m][0]];
            f32x4 hi = *(const f32x4*)&lds[buf][aoff[m][1]];
            a[m] = cvt8(lo, hi);
        }
#pragma unroll
        for (int n = 0; n < 4; ++n)
            b[n] = *(const bf16x8*)&lds[buf][boff[n]];
#pragma unroll
        for (int m = 0; m < 4; ++m)
#pragma unroll
            for (int n = 0; n < 4; ++n)
                acc[m][n] = __builtin_amdgcn_mfma_f32_16x16x32_bf16(a[m], b[n], acc[m][n], 0, 0, 0);
    };

    stage(0, 0);
    __syncthreads();
#pragma unroll 1
    for (int kt = 0; kt < E; kt += 64) {
        stage(1, kt + 32);
        compute(0);
        __syncthreads();
        if (kt + 64 < E) stage(0, kt + 64);
        compute(1);
        __syncthreads();
    }

    const int ccol0 = bn0 + wn * 64 + r16;
    const int crow0 = am0 + wm * 64 + kg * 4;
    const float sc = ga.scale ? ga.scale[0] : 1.f;
#pragma unroll
    for (int m = 0; m < 4; ++m)
#pragma unroll
        for (int n = 0; n < 4; ++n)
#pragma unroll
            for (int qq = 0; qq < 4; ++qq) {
                int row = crow0 + m * 16 + qq;
                int col = ccol0 + n * 16;
                short* p = (short*)(ga.C + (size_t)row * crstride) + col;
                *p = f2bfs(acc[m][n][qq] * sc);
            }
}

// ============ fused: out = LN(q_emb + (kv_emb @ M^T + c)) * g + b ============
// 1024 threads = 16 waves; wave w owns 64 rows x cols [w*64, w*64+64).
// acc = 64 VGPR/lane -> total ~120 -> 4 waves/SIMD (16 waves/CU).
// B (M, 2MB, L2/L3-resident): frags read DIRECTLY from global, no LDS, no
// barrier dependency. LDS holds only A (bf16, 2x4KB dbuf, [g][r] linear
// layout) + q prefetched as bf16 (128KB) + LN scratch. ONE barrier/phase.
// A & q loads ride 2 phases ahead in regs (aE/aO, qE/qO); all VMEM is
// compiler-tracked (its waitcnt insertion keeps prefetches in flight).
struct FArgs {
    const float* kv;   // [32768][1024] f32  (GEMM A)
    const short* M;    // [1024][1024] bf16  [n][k], alpha folded
    const float* c;    // [1024] f32, alpha folded
    const float* q;    // [32768][1024] f32  (residual emb)
    const float* g;
    const float* b;
    float* out;        // [32768][1024] f32
};

#define QLDS 8192
#define SLDS 139264
#define QLDS2 143360
#define CBLDS 147456

__global__ __launch_bounds__(1024) void fused_gemm_ln(FArgs f0, FArgs f1) {
    // pair-scheduling swizzle: consecutive slots on one XCD alternate tables at
    // the SAME mb -> the pair shares emb panels (kv of one = residual of other).
    const int bid = blockIdx.x;
    const int u = bid >> 3, xcd = bid & 7;
    const int z = u & 1;
    const int mb = xcd * 64 + (u >> 1);
    const FArgs fa = z ? f1 : f0;
    const int r0 = mb * 64;

    __shared__ __align__(16) char lds[147968];

    const int t = threadIdx.x;
    const int l = t & 63, w = t >> 6;       // wave 0..15
    const int r16 = l & 15, kg = l >> 4;

    // A-frag read base: layout [buf][g=4][row=64][16B]; + m*256 + buf*4096
    const int ard = kg * 1024 + r16 * 16;
    // A/q staging map: thread -> row tr, k-pair kp
    const int tr = t >> 4, kp = t & 15;
    const float* Ag = fa.kv + (size_t)(r0 + tr) * E + kp * 2;
    const float* Qg = fa.q + (size_t)(r0 + tr) * E + kp * 2;
    const int awr = ((kp >> 2) << 10) + tr * 16 + (kp & 3) * 4;  // + buf*4096
    const int qwr = QLDS + tr * 2048 + kp * 4;                   // + p*64

    // B-frag global element offsets (shorts), per nf; + p*32 per phase
    const short* Mb = fa.M;
    int boff[4];
#pragma unroll
    for (int nf = 0; nf < 4; ++nf)
        boff[nf] = (w * 64 + nf * 16 + r16) * E + kg * 8;

    f32x4 acc[4][4] = {};

    auto wrA = [&](int buf, f32x2 v) {
        *(int*)&lds[buf * 4096 + awr] = pack2(v);
    };
    auto wrQ = [&](int p, f32x2 v) {
        *(int*)&lds[qwr + p * 64] = pack2(v);
    };

    // ---- prologue: stage A k=0 -> buf0, k=32 -> buf1; preload 2-ahead regs ----
    {
        f32x2 a0 = *(const f32x2*)(Ag);
        f32x2 a1 = *(const f32x2*)(Ag + 32);
        wrA(0, a0);
        wrA(1, a1);
    }
    f32x2 aE = *(const f32x2*)(Ag + 64);   // commit at p=0 (k=64)
    f32x2 aO = *(const f32x2*)(Ag + 96);   // commit at p=1 (k=96)
    f32x2 qE = *(const f32x2*)(Qg);        // commit at p=0 (slice 0)
    f32x2 qO = *(const f32x2*)(Qg + 32);   // commit at p=1 (slice 1)
    asm volatile("s_waitcnt lgkmcnt(0)" ::: "memory");
    __builtin_amdgcn_sched_barrier(0);
    __builtin_amdgcn_s_barrier();
    __builtin_amdgcn_sched_barrier(0);

    auto phase = [&](int buf, int p, f32x2& aq, f32x2& qq) {
        bf16x8 a[4], b[4];
#pragma unroll
        for (int nf = 0; nf < 4; ++nf)
            b[nf] = *(const bf16x8*)(Mb + boff[nf] + p * 32);
#pragma unroll
        for (int m = 0; m < 4; ++m)
            a[m] = *(const bf16x8*)&lds[buf * 4096 + ard + m * 256];
        asm volatile("s_waitcnt lgkmcnt(0)" ::: "memory");
        __builtin_amdgcn_sched_barrier(0);
        __builtin_amdgcn_s_barrier();       // all waves done reading A-buf
        __builtin_amdgcn_sched_barrier(0);
        if (p + 2 < 32) wrA(buf, aq);       // restage A for p+2 (reg from p-2)
        wrQ(p, qq);                          // q slice p (reg from p-2)
        if (p + 4 < 32) aq = *(const f32x2*)(Ag + (p + 4) * 32);
        if (p + 2 < 32) qq = *(const f32x2*)(Qg + (p + 2) * 32);
        __builtin_amdgcn_s_setprio(1);
#pragma unroll
        for (int m = 0; m < 4; ++m)
#pragma unroll
            for (int nf = 0; nf < 4; ++nf)
                acc[m][nf] = __builtin_amdgcn_mfma_f32_16x16x32_bf16(a[m], b[nf], acc[m][nf], 0, 0, 0);
        __builtin_amdgcn_s_setprio(0);
    };

#pragma unroll 1
    for (int p = 0; p < 32; p += 2) {
        phase(0, p, aE, qE);
        phase(1, p + 1, aO, qO);
    }
    __syncthreads();   // all q-writes + MFMAs done; LN scratch safe

    // ---- epilogue: residual (q from LDS) + LayerNorm ----
    float* S  = (float*)(lds + SLDS);    // [64][16] row sums
    float* Q  = (float*)(lds + QLDS2);   // [64][16] row sumsq
    float* CB = (float*)(lds + CBLDS);   // [64][2] mean,rstd

    const int colbase = w * 64 + r16;
    float cf[4], gf[4], bf_[4];
#pragma unroll
    for (int nf = 0; nf < 4; ++nf) {
        cf[nf] = fa.c[colbase + nf * 16];
        gf[nf] = fa.g[colbase + nf * 16];
        bf_[nf] = fa.b[colbase + nf * 16];
    }

    float sum_[4][4] = {}, sq_[4][4] = {};
#pragma unroll
    for (int m = 0; m < 4; ++m) {
#pragma unroll
        for (int nf = 0; nf < 4; ++nf) {
#pragma unroll
            for (int qq = 0; qq < 4; ++qq) {
                int lrow = m * 16 + kg * 4 + qq;
                short qv = *(const short*)&lds[QLDS + lrow * 2048 + (colbase + nf * 16) * 2];
                float x = acc[m][nf][qq] + cf[nf] + bf2f(qv);
                acc[m][nf][qq] = x;
                sum_[m][qq] += x;
                sq_[m][qq] += x * x;
            }
        }
    }
#pragma unroll
    for (int m = 0; m < 4; ++m)
#pragma unroll
        for (int qq = 0; qq < 4; ++qq)
#pragma unroll
            for (int o = 1; o < 16; o <<= 1) {
                sum_[m][qq] += __shfl_xor(sum_[m][qq], o);
                sq_[m][qq] += __shfl_xor(sq_[m][qq], o);
            }
#pragma unroll
    for (int m = 0; m < 4; ++m)
#pragma unroll
        for (int qq = 0; qq < 4; ++qq)
            if (r16 == m * 4 + qq) {
                int lrow = m * 16 + kg * 4 + qq;
                S[lrow * 16 + w] = sum_[m][qq];
                Q[lrow * 16 + w] = sq_[m][qq];
            }
    __syncthreads();
    if (t < 64) {
        float ss = 0.f, qs = 0.f;
#pragma unroll
        for (int i = 0; i < 16; ++i) { ss += S[t * 16 + i]; qs += Q[t * 16 + i]; }
        float mean = ss * (1.0f / E);
        float var = qs * (1.0f / E) - mean * mean;
        CB[t * 2] = mean;
        CB[t * 2 + 1] = rsqrtf(var + 1e-5f);
    }
    __syncthreads();

#pragma unroll
    for (int m = 0; m < 4; ++m)
#pragma unroll
        for (int qq = 0; qq < 4; ++qq) {
            int lrow = m * 16 + kg * 4 + qq;
            float mean = CB[lrow * 2], rstd = CB[lrow * 2 + 1];
            float* op = fa.out + (size_t)(r0 + lrow) * E + colbase;
#pragma unroll
            for (int nf = 0; nf < 4; ++nf)
                op[nf * 16] = (acc[m][nf][qq] - mean) * rstd * gf[nf] + bf_[nf];
        }
}

extern "C" void kernel_launch(void* const* d_in, const int* in_sizes, int n_in,
                              void* d_out, int out_size, void* d_ws, size_t ws_size,
                              hipStream_t stream) {
    const float* user_emb = (const float*)d_in[0];
    const float* item_emb = (const float*)d_in[1];
    const float* u2i_in_w = (const float*)d_in[2];
    const float* u2i_in_b = (const float*)d_in[3];
    const float* u2i_out_w = (const float*)d_in[4];
    const float* u2i_out_b = (const float*)d_in[5];
    const float* i2u_in_w = (const float*)d_in[6];
    const float* i2u_in_b = (const float*)d_in[7];
    const float* i2u_out_w = (const float*)d_in[8];
    const float* i2u_out_b = (const float*)d_in[9];
    const float* user_g = (const float*)d_in[10];
    const float* user_b = (const float*)d_in[11];
    const float* item_g = (const float*)d_in[12];
    const float* item_b = (const float*)d_in[13];
    const float* alpha = (const float*)d_in[14];
    const float* beta = (const float*)d_in[15];

    float* out_u = (float*)d_out;
    float* out_i = out_u + (size_t)NB * E;

    // workspace (~8.4 MB)
    short* WvT1 = (short*)d_ws;
    short* WvT2 = WvT1 + (size_t)E * E;
    short* M1 = WvT2 + (size_t)E * E;
    short* M2 = M1 + (size_t)E * E;
    float* c1 = (float*)(M2 + (size_t)E * E);
    float* c2 = c1 + E;

    const dim3 b256(256);

    // 1) WvT = transpose(in_w[2E:3E]) in bf16
    wv_transpose<<<dim3(32, 32, 2), dim3(32, 8), 0, stream>>>(
        u2i_in_w + 2 * (size_t)E * E, WvT1, i2u_in_w + 2 * (size_t)E * E, WvT2);

    // 2) c = scale * (O @ bv + ob)
    bias_fuse<<<dim3(E, 1, 2), b256, 0, stream>>>(
        u2i_out_w, u2i_in_b + 2 * E, u2i_out_b, alpha, c1,
        i2u_out_w, i2u_in_b + 2 * E, i2u_out_b, beta, c2);

    // 3) M = scale * (O @ Wv)   bf16 [n][k]
    gemm_bt<<<dim3(8 * 8 * 2), b256, 0, stream>>>(
        GemmArgs{(const char*)u2i_out_w, WvT1, nullptr, alpha, (char*)M1},
        GemmArgs{(const char*)i2u_out_w, WvT2, nullptr, beta, (char*)M2},
        8, 4096, 2048);

    // 4) fused GEMM + residual + LayerNorm (1024 blocks x 1024 threads)
    fused_gemm_ln<<<dim3(1024), dim3(1024), 0, stream>>>(
        FArgs{item_emb, M1, c1, user_emb, user_g, user_b, out_u},
        FArgs{user_emb, M2, c2, item_emb, item_g, item_b, out_i});
}

// Round 10
// 399.608 us; speedup vs baseline: 1.3193x; 1.3193x over previous
//
#include <hip/hip_runtime.h>
#include <cstdint>
#include <cstddef>

#define E 1024
#define NB 32768
#define BM 128
#define BN 128

typedef __attribute__((ext_vector_type(4))) float f32x4;
typedef __attribute__((ext_vector_type(8))) short bf16x8;
typedef __attribute__((ext_vector_type(4))) short s16x4;

__device__ __forceinline__ short f2bfs(float x) {
    __bf16 h = (__bf16)x;
    return __builtin_bit_cast(short, h);
}
__device__ __forceinline__ float bf2f(short u) {
    union { unsigned u; float f; } v;
    v.u = ((unsigned)(unsigned short)u) << 16;
    return v.f;
}
__device__ __forceinline__ bf16x8 cvt8(f32x4 lo, f32x4 hi) {
    bf16x8 r;
#pragma unroll
    for (int j = 0; j < 4; ++j) { r[j] = f2bfs(lo[j]); r[j + 4] = f2bfs(hi[j]); }
    return r;
}

__device__ __forceinline__ void gload16(const void* g, void* l) {
    __builtin_amdgcn_global_load_lds(
        (__attribute__((address_space(1))) void*)g,
        (__attribute__((address_space(3))) void*)l, 16, 0, 0);
}

// ---------------- transpose f32 -> bf16 (Wv -> WvT) ----------------
__global__ __launch_bounds__(256) void wv_transpose(const float* W0, short* T0,
                                                    const float* W1, short* T1) {
    const float* W = blockIdx.z ? W1 : W0;
    short* T = blockIdx.z ? T1 : T0;
    __shared__ float tile[32][33];
    const int j0 = blockIdx.x * 32, i0 = blockIdx.y * 32;
    const int tx = threadIdx.x, ty = threadIdx.y; // (32,8)
#pragma unroll
    for (int r = 0; r < 4; ++r)
        tile[ty + 8 * r][tx] = W[(size_t)(i0 + ty + 8 * r) * E + j0 + tx];
    __syncthreads();
#pragma unroll
    for (int r = 0; r < 4; ++r)
        T[(size_t)(j0 + ty + 8 * r) * E + i0 + tx] = f2bfs(tile[tx][ty + 8 * r]);
}

// ---------------- c[n] = scale * (sum_i O[n][i]*bv[i] + ob[n]) ----------------
__global__ __launch_bounds__(256) void bias_fuse(const float* O0, const float* bv0, const float* ob0, const float* s0, float* c0,
                                                 const float* O1, const float* bv1, const float* ob1, const float* s1, float* c1) {
    const float* O  = blockIdx.z ? O1 : O0;
    const float* bv = blockIdx.z ? bv1 : bv0;
    const float* ob = blockIdx.z ? ob1 : ob0;
    const float* sc = blockIdx.z ? s1 : s0;
    float* c = blockIdx.z ? c1 : c0;
    const int n = blockIdx.x, t = threadIdx.x;
    float s = 0.f;
    for (int i = t; i < E; i += 256) s += O[(size_t)n * E + i] * bv[i];
#pragma unroll
    for (int o = 32; o; o >>= 1) s += __shfl_down(s, o);
    __shared__ float rs[4];
    if ((t & 63) == 0) rs[t >> 6] = s;
    __syncthreads();
    if (t == 0) c[n] = sc[0] * (rs[0] + rs[1] + rs[2] + rs[3] + ob[n]);
}

// ---------------- M-build GEMM (R3 gemm_bt<false>, verbatim): M = scale*(O @ WvT^T) ----------------
struct GemmArgs {
    const char* A;      // f32, row stride arstride
    const short* B;     // bf16 [n][k]
    const float* scale;
    char* C;            // bf16, row stride crstride
};

__global__ __launch_bounds__(256, 3) void gemm_m(GemmArgs g0, GemmArgs g1,
                                                 int mb, int arstride, int crstride) {
    const int nwg = gridDim.x;
    const int q = nwg >> 3;
    const int wgid = (blockIdx.x & 7) * q + (blockIdx.x >> 3);
    const int per = mb * 8;
    const int z = wgid / per;
    const int rem = wgid - z * per;
    const int bx = rem >> 3;
    const int by = rem & 7;
    GemmArgs ga = z ? g1 : g0;

    constexpr int ABYTES = 16384;
    __shared__ __align__(16) char lds[2][ABYTES + 8192];

    const int t = threadIdx.x;
    const int l = t & 63, w = t >> 6;
    const int am0 = bx * BM, bn0 = by * BN;

    const char* gA[4];
#pragma unroll
    for (int i = 0; i < 4; ++i) {
        int c = i * 4 + w;
        int row = c * 8 + (l >> 3);
        int slot = (l & 7) ^ (row & 7);
        gA[i] = ga.A + (size_t)(am0 + row) * arstride + slot * 16;
    }
    const short* gB[2];
#pragma unroll
    for (int i = 0; i < 2; ++i) {
        int c = i * 4 + w;
        int row = c * 16 + (l >> 2);
        int slot = (l & 3) ^ ((row >> 1) & 3);
        gB[i] = ga.B + (size_t)(bn0 + row) * E + slot * 8;
    }

    auto stage = [&](int buf, int kt) {
#pragma unroll
        for (int i = 0; i < 4; ++i)
            gload16(gA[i] + (size_t)kt * 4, &lds[buf][(i * 4 + w) * 1024]);
#pragma unroll
        for (int i = 0; i < 2; ++i)
            gload16(gB[i] + kt, &lds[buf][ABYTES + (i * 4 + w) * 1024]);
    };

    const int wm = w >> 1, wn = w & 1;
    const int r16 = l & 15, kg = l >> 4;
    int aoff[4][2], boff[4];
#pragma unroll
    for (int m = 0; m < 4; ++m) {
        int row = wm * 64 + m * 16 + r16;
        aoff[m][0] = row * 128 + ((kg * 2) ^ (row & 7)) * 16;
        aoff[m][1] = row * 128 + ((kg * 2 + 1) ^ (row & 7)) * 16;
    }
#pragma unroll
    for (int n = 0; n < 4; ++n) {
        int row = wn * 64 + n * 16 + r16;
        boff[n] = ABYTES + row * 64 + (kg ^ ((row >> 1) & 3)) * 16;
    }

    f32x4 acc[4][4] = {};

    auto compute = [&](int buf) {
        bf16x8 a[4], b[4];
#pragma unroll
        for (int m = 0; m < 4; ++m) {
            f32x4 lo = *(const f32x4*)&lds[buf][aoff[m][0]];
            f32x4 hi = *(const f32x4*)&lds[buf][aoff[m][1]];
            a[m] = cvt8(lo, hi);
        }
#pragma unroll
        for (int n = 0; n < 4; ++n)
            b[n] = *(const bf16x8*)&lds[buf][boff[n]];
#pragma unroll
        for (int m = 0; m < 4; ++m)
#pragma unroll
            for (int n = 0; n < 4; ++n)
                acc[m][n] = __builtin_amdgcn_mfma_f32_16x16x32_bf16(a[m], b[n], acc[m][n], 0, 0, 0);
    };

    stage(0, 0);
    __syncthreads();
#pragma unroll 1
    for (int kt = 0; kt < E; kt += 64) {
        stage(1, kt + 32);
        compute(0);
        __syncthreads();
        if (kt + 64 < E) stage(0, kt + 64);
        compute(1);
        __syncthreads();
    }

    const int ccol0 = bn0 + wn * 64 + r16;
    const int crow0 = am0 + wm * 64 + kg * 4;
    const float sc = ga.scale ? ga.scale[0] : 1.f;
#pragma unroll
    for (int m = 0; m < 4; ++m)
#pragma unroll
        for (int n = 0; n < 4; ++n)
#pragma unroll
            for (int qq = 0; qq < 4; ++qq) {
                int row = crow0 + m * 16 + qq;
                int col = ccol0 + n * 16;
                short* p = (short*)(ga.C + (size_t)row * crstride) + col;
                *p = f2bfs(acc[m][n][qq] * sc);
            }
}

// ============ att GEMM + residual: x = q + (kv @ M^T + c), x -> bf16 slots ============
// R3 geometry (128x128, 4 waves, 3 blocks/CU, 0-conflict swizzles, 189us measured),
// A reg-staged f32->bf16 (R4-proven commitA: load early, commit after barrier),
// B via global_load_lds DMA. Epilogue adds c + q and stores x bf16 into the
// lower 2KB of each 4KB d_out row slot (LN overwrites in place with f32).
struct AttArgs {
    const float* A;    // kv emb f32 [32768][1024]
    const short* B;    // M bf16 [n][k], alpha folded
    const float* c;    // [1024], alpha folded
    const float* q;    // residual emb f32
    char* xout;        // d_out region, 4KB row slots
};

__global__ __launch_bounds__(256, 3) void gemm_att(AttArgs g0, AttArgs g1) {
    // bijective XCD swizzle, grid 4096: XCDs 0-3 -> table0, 4-7 -> table1.
    const int bid = blockIdx.x;
    const int wgid = (bid & 7) * 512 + (bid >> 3);
    const int z = wgid >> 11;
    const int rem = wgid & 2047;
    const int bx = rem >> 3;
    const int by = rem & 7;
    AttArgs ga = z ? g1 : g0;

    // LDS 32KB: A 2x8KB @0 (bf16 64B rows), B 2x8KB @16384
    __shared__ __align__(16) char lds[32768];

    const int t = threadIdx.x;
    const int l = t & 63, w = t >> 6;
    const int r16 = l & 15, kg = l >> 4;
    const int am0 = bx * BM, bn0 = by * BN;

    // --- B DMA staging (R3-proven inverse-swizzled source) ---
    const short* gB[2];
#pragma unroll
    for (int i = 0; i < 2; ++i) {
        int c = i * 4 + w;
        int row = c * 16 + (l >> 2);
        int slot = (l & 3) ^ ((row >> 1) & 3);
        gB[i] = ga.B + (size_t)(bn0 + row) * E + slot * 8;
    }
    auto stageB = [&](int buf, int kt) {
#pragma unroll
        for (int i = 0; i < 2; ++i)
            gload16(gB[i] + kt, &lds[16384 + buf * 8192 + (i * 4 + w) * 1024]);
    };

    // --- A reg staging: thread t -> row t>>1, 16B units u0,u0+1 of that row ---
    const int arow = t >> 1, u0 = (t & 1) * 2;
    const int as_ = (arow >> 1) & 3;
    const float* Ag = ga.A + (size_t)(am0 + arow) * E + (t & 1) * 16;
    const int aw0 = arow * 64 + (u0 ^ as_) * 16;
    const int aw1 = arow * 64 + ((u0 + 1) ^ as_) * 16;

    f32x4 pa0, pa1, pa2, pa3;
    auto loadA = [&](int kt) {
        pa0 = *(const f32x4*)(Ag + kt);
        pa1 = *(const f32x4*)(Ag + kt + 4);
        pa2 = *(const f32x4*)(Ag + kt + 8);
        pa3 = *(const f32x4*)(Ag + kt + 12);
    };
    auto commitA = [&](int buf) {
        *(bf16x8*)&lds[buf * 8192 + aw0] = cvt8(pa0, pa1);
        *(bf16x8*)&lds[buf * 8192 + aw1] = cvt8(pa2, pa3);
    };

    // --- read-side swizzled offsets (R3 ABF16 layout: 0 conflicts measured) ---
    const int wm = w >> 1, wn = w & 1;
    int aoff[4], boff[4];
#pragma unroll
    for (int m = 0; m < 4; ++m) {
        int row = wm * 64 + m * 16 + r16;
        aoff[m] = row * 64 + (kg ^ ((row >> 1) & 3)) * 16;
    }
#pragma unroll
    for (int n = 0; n < 4; ++n) {
        int row = wn * 64 + n * 16 + r16;
        boff[n] = 16384 + row * 64 + (kg ^ ((row >> 1) & 3)) * 16;
    }

    f32x4 acc[4][4] = {};

    auto compute = [&](int buf) {
        bf16x8 a[4], b[4];
#pragma unroll
        for (int m = 0; m < 4; ++m)
            a[m] = *(const bf16x8*)&lds[buf * 8192 + aoff[m]];
#pragma unroll
        for (int n = 0; n < 4; ++n)
            b[n] = *(const bf16x8*)&lds[buf * 8192 + boff[n]];
#pragma unroll
        for (int m = 0; m < 4; ++m)
#pragma unroll
            for (int n = 0; n < 4; ++n)
                acc[m][n] = __builtin_amdgcn_mfma_f32_16x16x32_bf16(a[m], b[n], acc[m][n], 0, 0, 0);
    };

    // prologue: buf0 staged (B DMA + A commit k=0), pending regs hold k=32
    stageB(0, 0);
    loadA(0);
    commitA(0);
    loadA(32);
    __syncthreads();

#pragma unroll 1
    for (int kt = 0; kt < E; kt += 64) {
        stageB(1, kt + 32);
        commitA(1);                       // k = kt+32 (regs from previous half)
        if (kt + 64 < E) loadA(kt + 64);
        compute(0);
        __syncthreads();
        if (kt + 64 < E) {
            stageB(0, kt + 64);
            commitA(0);                   // k = kt+64
            if (kt + 96 < E) loadA(kt + 96);
        }
        compute(1);
        __syncthreads();
    }

    // ---- epilogue: x = acc + c + q, store bf16 into 4KB row slots ----
    const int ccol0 = bn0 + wn * 64 + r16;
    const int crow0 = am0 + wm * 64 + kg * 4;
    float cf[4];
#pragma unroll
    for (int n = 0; n < 4; ++n) cf[n] = ga.c[ccol0 + n * 16];
#pragma unroll
    for (int m = 0; m < 4; ++m)
#pragma unroll
        for (int n = 0; n < 4; ++n)
#pragma unroll
            for (int qq = 0; qq < 4; ++qq) {
                int row = crow0 + m * 16 + qq;
                int col = ccol0 + n * 16;
                float xv = acc[m][n][qq] + cf[n] + ga.q[(size_t)row * E + col];
                *(short*)(ga.xout + (size_t)row * 4096 + col * 2) = f2bfs(xv);
            }
}

// ---------------- LN in place: slot bf16 x[1024] -> f32 out[1024] ----------------
struct LnArgs {
    char* slot;       // d_out region, 4KB row slots (x bf16 in lower 2KB)
    const float* g;
    const float* b;
};

__global__ __launch_bounds__(256) void ln_apply(LnArgs l0, LnArgs l1) {
    LnArgs la = blockIdx.z ? l1 : l0;
    const int row = blockIdx.x;
    const int t = threadIdx.x;
    char* base = la.slot + (size_t)row * 4096;
    s16x4 xv = *(const s16x4*)(base + t * 8);
    f32x4 x;
#pragma unroll
    for (int j = 0; j < 4; ++j) x[j] = bf2f(xv[j]);
    float sum = x[0] + x[1] + x[2] + x[3];
    float sq = x[0] * x[0] + x[1] * x[1] + x[2] * x[2] + x[3] * x[3];
#pragma unroll
    for (int o = 32; o; o >>= 1) { sum += __shfl_down(sum, o); sq += __shfl_down(sq, o); }
    __shared__ float rs[8];
    const int lane = t & 63, wid = t >> 6;
    if (lane == 0) { rs[wid] = sum; rs[wid + 4] = sq; }
    __syncthreads();   // also orders: all x reads complete before writes below
    sum = rs[0] + rs[1] + rs[2] + rs[3];
    sq = rs[4] + rs[5] + rs[6] + rs[7];
    const float mean = sum * (1.0f / E);
    const float var = sq * (1.0f / E) - mean * mean;
    const float rstd = rsqrtf(var + 1e-5f);
    f32x4 gv = *(const f32x4*)(la.g + t * 4);
    f32x4 bv = *(const f32x4*)(la.b + t * 4);
    f32x4 o = (x - mean) * rstd * gv + bv;
    *(f32x4*)(base + t * 16) = o;
}

extern "C" void kernel_launch(void* const* d_in, const int* in_sizes, int n_in,
                              void* d_out, int out_size, void* d_ws, size_t ws_size,
                              hipStream_t stream) {
    const float* user_emb = (const float*)d_in[0];
    const float* item_emb = (const float*)d_in[1];
    const float* u2i_in_w = (const float*)d_in[2];
    const float* u2i_in_b = (const float*)d_in[3];
    const float* u2i_out_w = (const float*)d_in[4];
    const float* u2i_out_b = (const float*)d_in[5];
    const float* i2u_in_w = (const float*)d_in[6];
    const float* i2u_in_b = (const float*)d_in[7];
    const float* i2u_out_w = (const float*)d_in[8];
    const float* i2u_out_b = (const float*)d_in[9];
    const float* user_g = (const float*)d_in[10];
    const float* user_b = (const float*)d_in[11];
    const float* item_g = (const float*)d_in[12];
    const float* item_b = (const float*)d_in[13];
    const float* alpha = (const float*)d_in[14];
    const float* beta = (const float*)d_in[15];

    char* OU = (char*)d_out;                    // user rows: x/out slots 4KB
    char* OI = OU + (size_t)NB * 4096;          // item rows

    // workspace (~8.4 MB)
    short* WvT1 = (short*)d_ws;
    short* WvT2 = WvT1 + (size_t)E * E;
    short* M1 = WvT2 + (size_t)E * E;
    short* M2 = M1 + (size_t)E * E;
    float* c1 = (float*)(M2 + (size_t)E * E);
    float* c2 = c1 + E;

    const dim3 b256(256);

    // 1) WvT = transpose(in_w[2E:3E]) in bf16
    wv_transpose<<<dim3(32, 32, 2), dim3(32, 8), 0, stream>>>(
        u2i_in_w + 2 * (size_t)E * E, WvT1, i2u_in_w + 2 * (size_t)E * E, WvT2);

    // 2) c = scale * (O @ bv + ob)
    bias_fuse<<<dim3(E, 1, 2), b256, 0, stream>>>(
        u2i_out_w, u2i_in_b + 2 * E, u2i_out_b, alpha, c1,
        i2u_out_w, i2u_in_b + 2 * E, i2u_out_b, beta, c2);

    // 3) M = scale * (O @ Wv)   bf16 [n][k]
    gemm_m<<<dim3(8 * 8 * 2), b256, 0, stream>>>(
        GemmArgs{(const char*)u2i_out_w, WvT1, alpha, (char*)M1},
        GemmArgs{(const char*)i2u_out_w, WvT2, beta, (char*)M2},
        8, 4096, 2048);

    // 4) x = q + (kv @ M^T + c) -> bf16 slots (4096 blocks, 3 blocks/CU)
    gemm_att<<<dim3(4096), b256, 0, stream>>>(
        AttArgs{item_emb, M1, c1, user_emb, OU},
        AttArgs{user_emb, M2, c2, item_emb, OI});

    // 5) out = LN(x) * g + b  (in place: bf16 -> f32, 384 MB total)
    ln_apply<<<dim3(NB, 1, 2), b256, 0, stream>>>(
        LnArgs{OU, user_g, user_b},
        LnArgs{OI, item_g, item_b});
}